// Round 5
// baseline (77.780 us; speedup 1.0000x reference)
//
#include <hip/hip_runtime.h>
#include <hip/hip_bf16.h>

// y[b,i,j] = s[b,i] + s[b,j] - 2 * sum_k (w[b,k]*V[b,i,k]) * V[b,j,k]
//   w = max(G,0)^(2t),  s[b,i] = sum_k (w*V)[b,i,k]*V[b,i,k]
// bs=4, r=4096, d=64. Output 268 MB fp32 -> write-bandwidth bound.
// R4 -> R5: grid-axis swap so consecutive blocks share one B panel
// (i walks fastest, j-column/batch slow). B panel (32 KB) stays L2-hot
// with a short reuse distance despite the 268 MB write stream evicting
// L2; L3 read traffic ~295 MB -> ~50 MB. NT stores restored (don't
// write-allocate over the hot B panel).

typedef __attribute__((ext_vector_type(8))) short bf16x8;   // 8 bf16 = 4 VGPRs
typedef __attribute__((ext_vector_type(4))) float f32x4;

constexpr int BS = 4, R = 4096, D = 64;
constexpr int LS = 260;   // LDS row stride (floats): 16B-aligned rows, 2-way max bank conflict (free)

// ---------------------------------------------------------------- prep ------
// One wave per row (64 lanes == d). Emits bf16(V), bf16(w*V), fp32 s.
__global__ __launch_bounds__(256) void prep_kernel(
    const float* __restrict__ G, const float* __restrict__ V,
    const float* __restrict__ wt,
    __hip_bfloat16* __restrict__ vw_bf, __hip_bfloat16* __restrict__ v_bf,
    float* __restrict__ s)
{
    int row  = blockIdx.x * 4 + (threadIdx.x >> 6);   // global row in [0, BS*R)
    int lane = threadIdx.x & 63;                       // k index (d == 64)
    if (row >= BS * R) return;
    int b = row / R;

    float t2 = 2.0f * wt[0];
    float g  = fmaxf(G[b * D + lane], 0.0f);
    float w  = powf(g, t2);                            // matches jnp: 0^0 == 1
    float v  = V[(size_t)row * D + lane];

    __hip_bfloat16 vb  = __float2bfloat16(v);
    __hip_bfloat16 vwb = __float2bfloat16(w * v);
    v_bf [(size_t)row * D + lane] = vb;
    vw_bf[(size_t)row * D + lane] = vwb;

    // s from the same bf16-rounded values -> diagonal cancels vs MFMA cross
    float prod = __bfloat162float(vwb) * __bfloat162float(vb);
    #pragma unroll
    for (int off = 32; off; off >>= 1) prod += __shfl_down(prod, off);
    if (lane == 0) s[row] = prod;
}

// ---------------------------------------------------------------- dist ------
// Wave tile: 32 (i) x 64 (j). Block: 4 waves along j -> 32x256.
// Grid: (R/32 i-blocks [FAST], R/256 j-cols, BS) — consecutive blocks
// share the same B panel and stream A.
// MFMA 16x16x32 bf16 layouts (HW-verified, learn_hip m89/m91/m97):
//   A: lane holds A[row=l&15][k=(l>>4)*8 + 0..7]   (contiguous 16B)
//   B: lane holds B[k=(l>>4)*8 + 0..7][col=l&15] == V[j0+(l&15)][k...] for B=V^T
//   C/D: col = l&15, row = (l>>4)*4 + reg
// Epilogue: y -> LDS[32][256(+4)] -> full-row 1KB coalesced NT stores.
__global__ __launch_bounds__(256) void dist_kernel(
    const short* __restrict__ vw_bf, const short* __restrict__ v_bf,
    const float* __restrict__ s, float* __restrict__ out)
{
    __shared__ float lds[32 * LS];   // 33.3 KB

    int lane = threadIdx.x & 63;
    int wave = threadIdx.x >> 6;
    int b  = blockIdx.z;
    int i0 = blockIdx.x * 32;        // FAST axis: consecutive blocks walk i
    int jb = blockIdx.y * 256;
    int j0 = jb + wave * 64;

    const short* A  = vw_bf + ((size_t)b * R + i0) * D;   // 32 rows x 64
    const short* B  = v_bf  + ((size_t)b * R + j0) * D;   // 64 rows x 64
    const float* sb = s + (size_t)b * R;

    int lrow = lane & 15;
    int kgrp = lane >> 4;          // 0..3

    // A fragments: 2 row-blocks x 2 K-steps
    bf16x8 a[2][2];
    #pragma unroll
    for (int rb = 0; rb < 2; ++rb)
        #pragma unroll
        for (int ks = 0; ks < 2; ++ks)
            a[rb][ks] = *(const bf16x8*)(A + (rb * 16 + lrow) * D + ks * 32 + kgrp * 8);

    f32x4 acc[2][4];
    #pragma unroll
    for (int rb = 0; rb < 2; ++rb)
        #pragma unroll
        for (int jt = 0; jt < 4; ++jt)
            acc[rb][jt] = f32x4{0.f, 0.f, 0.f, 0.f};

    #pragma unroll
    for (int jt = 0; jt < 4; ++jt) {
        const short* Bt = B + jt * 16 * D;
        bf16x8 b0 = *(const bf16x8*)(Bt + lrow * D +      kgrp * 8);
        bf16x8 b1 = *(const bf16x8*)(Bt + lrow * D + 32 + kgrp * 8);
        #pragma unroll
        for (int rb = 0; rb < 2; ++rb) {
            acc[rb][jt] = __builtin_amdgcn_mfma_f32_16x16x32_bf16(a[rb][0], b0, acc[rb][jt], 0, 0, 0);
            acc[rb][jt] = __builtin_amdgcn_mfma_f32_16x16x32_bf16(a[rb][1], b1, acc[rb][jt], 0, 0, 0);
        }
    }

    // epilogue part 1: y = si + sj - 2*acc  -> LDS tile
    float si_lane = sb[i0 + (lane & 31)];    // lane c (c<32) holds s[i0+c]
    #pragma unroll
    for (int rb = 0; rb < 2; ++rb) {
        #pragma unroll
        for (int rg = 0; rg < 4; ++rg) {
            int row  = rb * 16 + kgrp * 4 + rg;          // 0..31
            float si = __shfl(si_lane, row);
            #pragma unroll
            for (int jt = 0; jt < 4; ++jt) {
                float sj = sb[j0 + jt * 16 + lrow];
                float y  = si + sj - 2.0f * acc[rb][jt][rg];
                lds[row * LS + wave * 64 + jt * 16 + lrow] = y;
            }
        }
    }

    __syncthreads();

    // epilogue part 2: full-row coalesced stores. Wave w -> rows w*8..w*8+7.
    // Each instruction: 64 lanes x 16B = one contiguous 1KB-aligned segment.
    float* outb = out + ((size_t)b * R + i0) * R + jb;
    #pragma unroll
    for (int r = 0; r < 8; ++r) {
        int row = wave * 8 + r;
        f32x4 v = *(const f32x4*)&lds[row * LS + lane * 4];
        __builtin_nontemporal_store(v, (f32x4*)(outb + (size_t)row * R + lane * 4));
    }
}

// --------------------------------------------------------------------------
extern "C" void kernel_launch(void* const* d_in, const int* in_sizes, int n_in,
                              void* d_out, int out_size, void* d_ws, size_t ws_size,
                              hipStream_t stream) {
    const float* G  = (const float*)d_in[0];
    const float* V  = (const float*)d_in[1];
    const float* wt = (const float*)d_in[2];
    float* out = (float*)d_out;

    char* ws = (char*)d_ws;
    __hip_bfloat16* vw_bf = (__hip_bfloat16*)ws;                              // 2 MB
    __hip_bfloat16* v_bf  = (__hip_bfloat16*)(ws + (size_t)BS * R * D * 2);   // 2 MB
    float*          s     = (float*)        (ws + (size_t)BS * R * D * 4);    // 64 KB

    prep_kernel<<<BS * R / 4, 256, 0, stream>>>(G, V, wt, vw_bf, v_bf, s);

    dim3 grid(R / 32, R / 256, BS);   // i fastest -> B-panel reuse across blocks
    dist_kernel<<<grid, 256, 0, stream>>>((const short*)vw_bf, (const short*)v_bf,
                                          s, out);
}

// Round 6
// 66.724 us; speedup vs baseline: 1.1657x; 1.1657x over previous
//
#include <hip/hip_runtime.h>
#include <hip/hip_bf16.h>

// y[b,i,j] = s[b,i] + s[b,j] - 2 * sum_k (w[b,k]*V[b,i,k]) * V[b,j,k]
//   w = max(G,0)^(2t),  s[b,i] = sum_k (w*V)[b,i,k]*V[b,i,k]
// bs=4, r=4096, d=64. Output 268 MB fp32 -> write-bandwidth bound.
// R5 -> R6: (a) revert to j-fastest grid (R5 showed write-stream locality
// beats B-reuse); (b) 128x256 block tile via 512 threads / 8 waves of
// 64x64 -> read amplification 1.125 -> 0.375 (295 MB -> ~100 MB reads).
// Epilogue: LDS-staged full-line stores in two 64-row chunks (66.5 KB LDS,
// 2 blocks/CU for cross-block overlap).

typedef __attribute__((ext_vector_type(8))) short bf16x8;   // 8 bf16 = 4 VGPRs
typedef __attribute__((ext_vector_type(4))) float f32x4;

constexpr int BS = 4, R = 4096, D = 64;
constexpr int LS = 260;   // LDS row stride (floats): 16B-aligned rows, 2-way max bank conflict (free)

// ---------------------------------------------------------------- prep ------
// One wave per row (64 lanes == d). Emits bf16(V), bf16(w*V), fp32 s.
__global__ __launch_bounds__(256) void prep_kernel(
    const float* __restrict__ G, const float* __restrict__ V,
    const float* __restrict__ wt,
    __hip_bfloat16* __restrict__ vw_bf, __hip_bfloat16* __restrict__ v_bf,
    float* __restrict__ s)
{
    int row  = blockIdx.x * 4 + (threadIdx.x >> 6);   // global row in [0, BS*R)
    int lane = threadIdx.x & 63;                       // k index (d == 64)
    if (row >= BS * R) return;
    int b = row / R;

    float t2 = 2.0f * wt[0];
    float g  = fmaxf(G[b * D + lane], 0.0f);
    float w  = powf(g, t2);                            // matches jnp: 0^0 == 1
    float v  = V[(size_t)row * D + lane];

    __hip_bfloat16 vb  = __float2bfloat16(v);
    __hip_bfloat16 vwb = __float2bfloat16(w * v);
    v_bf [(size_t)row * D + lane] = vb;
    vw_bf[(size_t)row * D + lane] = vwb;

    // s from the same bf16-rounded values -> diagonal cancels vs MFMA cross
    float prod = __bfloat162float(vwb) * __bfloat162float(vb);
    #pragma unroll
    for (int off = 32; off; off >>= 1) prod += __shfl_down(prod, off);
    if (lane == 0) s[row] = prod;
}

// ---------------------------------------------------------------- dist ------
// Block: 512 threads = 8 waves, arranged 2 (i) x 4 (j); wave tile 64x64.
// Block tile 128 (i) x 256 (j). Grid: (R/256 j [FAST], R/128 i, BS).
// MFMA 16x16x32 bf16 layouts (HW-verified, learn_hip m89/m91/m97):
//   A: lane holds A[row=l&15][k=(l>>4)*8 + 0..7]   (contiguous 16B)
//   B: lane holds B[k=(l>>4)*8 + 0..7][col=l&15] == V[j0+(l&15)][k...] for B=V^T
//   C/D: col = l&15, row = (l>>4)*4 + reg
// Epilogue: two 64-row chunks: y -> LDS[64][260] -> full-row 1KB NT stores.
__global__ __launch_bounds__(512) void dist_kernel(
    const short* __restrict__ vw_bf, const short* __restrict__ v_bf,
    const float* __restrict__ s, float* __restrict__ out)
{
    __shared__ float lds[64 * LS];   // 66.5 KB -> 2 blocks/CU

    int lane = threadIdx.x & 63;
    int wave = threadIdx.x >> 6;     // 0..7
    int wr   = wave >> 2;            // 0..1  (i half)
    int wc   = wave & 3;             // 0..3  (j quarter)

    int b  = blockIdx.z;
    int jb = blockIdx.x * 256;       // FAST axis: j -> contiguous write window
    int i0 = blockIdx.y * 128;

    const short* A  = vw_bf + ((size_t)b * R + i0 + wr * 64) * D;   // 64 rows
    const short* B  = v_bf  + ((size_t)b * R + jb + wc * 64) * D;   // 64 rows
    const float* sb = s + (size_t)b * R;

    int lrow = lane & 15;
    int kgrp = lane >> 4;            // 0..3

    // A fragments: 4 row-blocks x 2 K-steps
    bf16x8 a[4][2];
    #pragma unroll
    for (int rb = 0; rb < 4; ++rb)
        #pragma unroll
        for (int ks = 0; ks < 2; ++ks)
            a[rb][ks] = *(const bf16x8*)(A + (rb * 16 + lrow) * D + ks * 32 + kgrp * 8);

    f32x4 acc[4][4];
    #pragma unroll
    for (int rb = 0; rb < 4; ++rb)
        #pragma unroll
        for (int jt = 0; jt < 4; ++jt)
            acc[rb][jt] = f32x4{0.f, 0.f, 0.f, 0.f};

    #pragma unroll
    for (int jt = 0; jt < 4; ++jt) {
        const short* Bt = B + jt * 16 * D;
        bf16x8 b0 = *(const bf16x8*)(Bt + lrow * D +      kgrp * 8);
        bf16x8 b1 = *(const bf16x8*)(Bt + lrow * D + 32 + kgrp * 8);
        #pragma unroll
        for (int rb = 0; rb < 4; ++rb) {
            acc[rb][jt] = __builtin_amdgcn_mfma_f32_16x16x32_bf16(a[rb][0], b0, acc[rb][jt], 0, 0, 0);
            acc[rb][jt] = __builtin_amdgcn_mfma_f32_16x16x32_bf16(a[rb][1], b1, acc[rb][jt], 0, 0, 0);
        }
    }

    // per-lane row sums for this wave's 64 rows
    float si_lane = sb[i0 + wr * 64 + lane];

    float* outb = out + ((size_t)b * R + i0) * R + jb;

    #pragma unroll
    for (int c = 0; c < 2; ++c) {
        // chunk c covers block rows c*64 .. c*64+63 (i.e. waves with wr==c)
        if (wr == c) {
            #pragma unroll
            for (int rb = 0; rb < 4; ++rb) {
                #pragma unroll
                for (int rg = 0; rg < 4; ++rg) {
                    int rl = rb * 16 + kgrp * 4 + rg;          // 0..63 local row
                    float si = __shfl(si_lane, rl);
                    #pragma unroll
                    for (int jt = 0; jt < 4; ++jt) {
                        float sj = sb[jb + wc * 64 + jt * 16 + lrow];
                        float y  = si + sj - 2.0f * acc[rb][jt][rg];
                        lds[rl * LS + wc * 64 + jt * 16 + lrow] = y;
                    }
                }
            }
        }
        __syncthreads();

        // all 8 waves store chunk c: wave w -> rows w*8..w*8+7 of the chunk.
        // Each instruction: 64 lanes x 16B = one contiguous 1KB segment.
        #pragma unroll
        for (int r = 0; r < 8; ++r) {
            int rl = wave * 8 + r;
            f32x4 v = *(const f32x4*)&lds[rl * LS + lane * 4];
            __builtin_nontemporal_store(v,
                (f32x4*)(outb + (size_t)(c * 64 + rl) * R + lane * 4));
        }
        if (c == 0) __syncthreads();   // protect LDS before chunk-1 writes
    }
}

// --------------------------------------------------------------------------
extern "C" void kernel_launch(void* const* d_in, const int* in_sizes, int n_in,
                              void* d_out, int out_size, void* d_ws, size_t ws_size,
                              hipStream_t stream) {
    const float* G  = (const float*)d_in[0];
    const float* V  = (const float*)d_in[1];
    const float* wt = (const float*)d_in[2];
    float* out = (float*)d_out;

    char* ws = (char*)d_ws;
    __hip_bfloat16* vw_bf = (__hip_bfloat16*)ws;                              // 2 MB
    __hip_bfloat16* v_bf  = (__hip_bfloat16*)(ws + (size_t)BS * R * D * 2);   // 2 MB
    float*          s     = (float*)        (ws + (size_t)BS * R * D * 4);    // 64 KB

    prep_kernel<<<BS * R / 4, 256, 0, stream>>>(G, V, wt, vw_bf, v_bf, s);

    dim3 grid(R / 256, R / 128, BS);   // j fastest -> contiguous write window
    dist_kernel<<<grid, 512, 0, stream>>>((const short*)vw_bf, (const short*)v_bf,
                                          s, out);
}